// Round 1
// baseline (95.135 us; speedup 1.0000x reference)
//
#include <hip/hip_runtime.h>
#include <stdint.h>

#define T_DIM 256
#define B_DIM 8
#define CIN   256
#define COUT  256
#define NE    64
#define RD    64
#define NTOK  2048
#define KTOT  16384

typedef __attribute__((ext_vector_type(8))) short bf16x8;
typedef __attribute__((ext_vector_type(4))) float f32x4;

// ---------- helpers ----------
__device__ inline unsigned short f2bf(float f) {
    uint32_t u = __float_as_uint(f);
    uint32_t r = (u + 0x7FFFu + ((u >> 16) & 1u)) >> 16;   // RNE, finite inputs
    return (unsigned short)r;
}

__device__ inline float wave_sum(float v) {
    #pragma unroll
    for (int m = 1; m < 64; m <<= 1) v += __shfl_xor(v, m, 64);
    return v;
}
__device__ inline float wave_max(float v) {
    #pragma unroll
    for (int m = 1; m < 64; m <<= 1) v = fmaxf(v, __shfl_xor(v, m, 64));
    return v;
}

__device__ inline uint32_t rotl32(uint32_t v, int d) { return (v << d) | (v >> (32 - d)); }

// Threefry-2x32, key = (0, 42), matching JAX's threefry2x32 exactly.
__device__ inline void threefry_0_42(uint32_t c0, uint32_t c1, uint32_t& o0, uint32_t& o1) {
    const uint32_t ks0 = 0u, ks1 = 42u, ks2 = 0u ^ 42u ^ 0x1BD11BDAu;
    uint32_t x0 = c0 + ks0, x1 = c1 + ks1;
#define TF_R(r) { x0 += x1; x1 = rotl32(x1, r); x1 ^= x0; }
    TF_R(13) TF_R(15) TF_R(26) TF_R(6)
    x0 += ks1; x1 += ks2 + 1u;
    TF_R(17) TF_R(29) TF_R(16) TF_R(24)
    x0 += ks2; x1 += ks0 + 2u;
    TF_R(13) TF_R(15) TF_R(26) TF_R(6)
    x0 += ks0; x1 += ks1 + 3u;
    TF_R(17) TF_R(29) TF_R(16) TF_R(24)
    x0 += ks1; x1 += ks2 + 4u;
    TF_R(13) TF_R(15) TF_R(26) TF_R(6)
    x0 += ks2; x1 += ks0 + 5u;
#undef TF_R
    o0 = x0; o1 = x1;
}

// ---------- kernel 1: pack pw_w (NE, COUT*CIN) fp32 -> Bp (COUT, NE*CIN) bf16 ----------
__global__ __launch_bounds__(256) void pack_b_kernel(const float* __restrict__ pw,
                                                     unsigned short* __restrict__ Bp) {
    int tid = blockIdx.x * 256 + threadIdx.x;   // 1,048,576 threads, 4 elems each
    int i4 = tid & 63;
    int o  = (tid >> 6) & 255;
    int e  = tid >> 14;
    float4 v = *(const float4*)(pw + ((size_t)e << 16) + (o << 8) + (i4 << 2));
    ushort4 u;
    u.x = f2bf(v.x); u.y = f2bf(v.y); u.z = f2bf(v.z); u.w = f2bf(v.w);
    *(ushort4*)(Bp + ((size_t)o << 14) + (e << 8) + (i4 << 2)) = u;
}

// ---------- kernel 2: per-token VQ: k-proj, distances, gumbel-softmax, quantize ----------
__global__ __launch_bounds__(64) void vq_kernel(
    const float* __restrict__ x, const float* __restrict__ mw,
    const float* __restrict__ mb, const float* __restrict__ cent,
    float* __restrict__ resp_out, float* __restrict__ commit_out)
{
    __shared__ float xs[CIN];
    __shared__ float cs[NE][RD + 1];   // +1 pad: kills column-read bank conflicts
    __shared__ float ksh[RD];
    __shared__ float rs[NE];

    const int tb = blockIdx.x;
    const int t  = threadIdx.x;

    ((float4*)xs)[t] = ((const float4*)(x + (size_t)tb * CIN))[t];
    #pragma unroll
    for (int j = 0; j < 16; ++j) {
        int fidx = (j << 6) + t;                 // linear float4 index -> coalesced
        float4 v = ((const float4*)cent)[fidx];
        int row = fidx >> 4, c0 = (fidx & 15) << 2;
        cs[row][c0] = v.x; cs[row][c0 + 1] = v.y; cs[row][c0 + 2] = v.z; cs[row][c0 + 3] = v.w;
    }
    __syncthreads();

    // k[t] = x_row . map_w[t] + map_b[t]
    float kr = mb[t];
    const float4* mwr = (const float4*)(mw + (size_t)t * CIN);
    #pragma unroll 8
    for (int j = 0; j < 64; ++j) {
        float4 wv = mwr[j];
        kr += wv.x * xs[(j << 2)] + wv.y * xs[(j << 2) + 1]
            + wv.z * xs[(j << 2) + 2] + wv.w * xs[(j << 2) + 3];
    }
    ksh[t] = kr;
    float kk = wave_sum(kr * kr);
    __syncthreads();

    // d[t] = ||k||^2 + ||c_t||^2 - 2 k.c_t
    float cc = 0.f, dt = 0.f;
    #pragma unroll 8
    for (int r = 0; r < 64; ++r) {
        float cv = cs[t][r];
        cc += cv * cv;
        dt += ksh[r] * cv;
    }
    float d = kk + cc - 2.f * dt;

    // gumbel noise, bit-exact with jax.random.gumbel(key(42), (2048,64), f32)
    uint32_t fidx = (uint32_t)((tb << 6) + t);
    uint32_t cnt  = fidx < 65536u ? fidx : fidx - 65536u;
    uint32_t o0, o1;
    threefry_0_42(cnt, cnt + 65536u, o0, o1);
    uint32_t bits = fidx < 65536u ? o0 : o1;
    float uf = __uint_as_float((bits >> 9) | 0x3f800000u) - 1.0f;
    uf = fmaxf(uf, 1.17549435e-38f);
    float g = -logf(-logf(uf));

    // softmax over 64 lanes of (g - d)/tau
    float sv = (g - d) * 1.0f;   // TAU = 1
    float mx = wave_max(sv);
    float p  = expf(sv - mx);
    float ps = wave_sum(p);
    float rv = p / ps;
    resp_out[(tb << 6) + t] = rv;
    rs[t] = rv;
    __syncthreads();

    // quantized[t] = sum_e resp[e]*cent[e][t]; commit partial = sum_r (k[r]-q[r])^2
    float q = 0.f;
    #pragma unroll 8
    for (int e2 = 0; e2 < 64; ++e2) q += rs[e2] * cs[e2][t];
    float df = kr - q;
    float sq = wave_sum(df * df);
    if (t == 0) commit_out[tb] = sq;
}

// ---------- kernel 3: loss scalar ----------
__global__ __launch_bounds__(1024) void loss_kernel(const float* __restrict__ resp,
                                                    const float* __restrict__ commit_part,
                                                    float* __restrict__ loss_out)
{
    const int t = threadIdx.x;
    const int e = t & 63, wv = t >> 6;   // 16 row groups
    float s0 = 0, s1 = 0, s2 = 0, s3 = 0;
    for (int r = wv; r < NTOK; r += 64) {
        s0 += resp[(r)      * 64 + e];
        s1 += resp[(r + 16) * 64 + e];
        s2 += resp[(r + 32) * 64 + e];
        s3 += resp[(r + 48) * 64 + e];
    }
    __shared__ float pss[16][64];
    __shared__ float cps[1024];
    pss[wv][e] = (s0 + s1) + (s2 + s3);
    float csum = 0;
    for (int i = t; i < NTOK; i += 1024) csum += commit_part[i];
    cps[t] = csum;
    __syncthreads();
    if (t < 64) {
        float imp = 0, ct = 0;
        #pragma unroll
        for (int g2 = 0; g2 < 16; ++g2) { imp += pss[g2][t]; ct += cps[(g2 << 6) + t]; }
        ct = wave_sum(ct);
        float tot  = wave_sum(imp);
        float mean = tot * (1.0f / 64.f);
        float dv   = imp - mean;
        float var  = wave_sum(dv * dv) * (1.0f / 63.f);
        if (t == 0) {
            float mse = ct * (1.0f / (float)(NTOK * RD));
            float imp_loss = sqrtf(var) / mean;
            // commitment and kmeans losses are numerically identical forward
            loss_out[0] = (0.25f + 1.0f) * mse + 30.0f * imp_loss;
        }
    }
}

// ---------- kernel 4: fused MoE GEMM  C[2048,256] = A[2048,16384] x B[16384,256] ----------
// A[m, e*256+i] = resp[m,e] * x[m,i]  (built on the fly, fp32->bf16)
// B stored N-major: Bp[o, k], k contiguous.
#define BM 128
#define BN 128
#define BK 64

__global__ __launch_bounds__(256, 2) void gemm_kernel(
    const float* __restrict__ x, const float* __restrict__ resp,
    const unsigned short* __restrict__ Bp, float* __restrict__ partial, int ksteps)
{
    __shared__ bf16x8 AsV[1024];  // 16 KB: [128 rows][8 slots of 16B], XOR-swizzled
    __shared__ bf16x8 BsV[1024];  // 16 KB: rows are output-cols n, k contiguous
    char* As = (char*)AsV;
    char* Bs = (char*)BsV;

    const int tid  = threadIdx.x;
    const int lane = tid & 63;
    const int w    = tid >> 6;
    const int mt = blockIdx.x >> 1, nt = blockIdx.x & 1;
    const int m0 = mt << 7, n0 = nt << 7;
    const int kbase = blockIdx.y * ksteps * BK;

    const int wm = (w >> 1) << 6, wn = (w & 1) << 6;
    const int krow = lane & 15, kq = lane >> 4;

    f32x4 acc[4][4] = {};

    for (int ks = 0; ks < ksteps; ++ks) {
        const int kg = kbase + (ks << 6);
        const int e  = kg >> 8;     // expert index (BK=64 never straddles experts)
        const int i0 = kg & 255;
        __syncthreads();
        #pragma unroll
        for (int c = 0; c < 4; ++c) {
            const int chunk = (c << 8) + tid;     // 1024 chunks of 16B per tile
            const int row = chunk >> 3;
            const int sl  = chunk & 7;
            const int st  = sl ^ (row & 7);       // XOR swizzle (16B granules)
            {   // A: scale x by resp, convert to bf16
                const float rvs = resp[((m0 + row) << 6) + e];
                const float* xr = x + (size_t)(m0 + row) * CIN + i0 + (sl << 3);
                float4 v0 = *(const float4*)xr;
                float4 v1 = *(const float4*)(xr + 4);
                bf16x8 bv;
                bv[0] = (short)f2bf(v0.x * rvs); bv[1] = (short)f2bf(v0.y * rvs);
                bv[2] = (short)f2bf(v0.z * rvs); bv[3] = (short)f2bf(v0.w * rvs);
                bv[4] = (short)f2bf(v1.x * rvs); bv[5] = (short)f2bf(v1.y * rvs);
                bv[6] = (short)f2bf(v1.z * rvs); bv[7] = (short)f2bf(v1.w * rvs);
                *(bf16x8*)(As + (row << 7) + (st << 4)) = bv;
            }
            {   // B: already bf16, copy 16B
                bf16x8 bv = *(const bf16x8*)(Bp + ((size_t)(n0 + row) << 14) + kg + (sl << 3));
                *(bf16x8*)(Bs + (row << 7) + (st << 4)) = bv;
            }
        }
        __syncthreads();
        #pragma unroll
        for (int s = 0; s < 2; ++s) {
            bf16x8 af[4], bfr[4];
            #pragma unroll
            for (int mi = 0; mi < 4; ++mi) {
                const int row  = wm + (mi << 4) + krow;
                const int slot = ((s << 2) + kq) ^ (row & 7);
                af[mi] = *(const bf16x8*)(As + (row << 7) + (slot << 4));
            }
            #pragma unroll
            for (int ni = 0; ni < 4; ++ni) {
                const int row  = wn + (ni << 4) + krow;
                const int slot = ((s << 2) + kq) ^ (row & 7);
                bfr[ni] = *(const bf16x8*)(Bs + (row << 7) + (slot << 4));
            }
            #pragma unroll
            for (int mi = 0; mi < 4; ++mi)
                #pragma unroll
                for (int ni = 0; ni < 4; ++ni)
                    acc[mi][ni] = __builtin_amdgcn_mfma_f32_16x16x32_bf16(
                        af[mi], bfr[ni], acc[mi][ni], 0, 0, 0);
        }
    }

    float* pout = partial + (size_t)blockIdx.y * (NTOK * COUT);
    #pragma unroll
    for (int mi = 0; mi < 4; ++mi) {
        const int rb = m0 + wm + (mi << 4) + (kq << 2);   // C/D: row=(lane>>4)*4+j
        #pragma unroll
        for (int ni = 0; ni < 4; ++ni) {
            const int col = n0 + wn + (ni << 4) + krow;   // col = lane&15
            #pragma unroll
            for (int j = 0; j < 4; ++j)
                pout[(size_t)(rb + j) * COUT + col] = acc[mi][ni][j];
        }
    }
}

// ---------- kernel 5: split-K reduce + bias ----------
__global__ __launch_bounds__(256) void reduce_kernel(const float* __restrict__ partial,
                                                     const float* __restrict__ bias,
                                                     float* __restrict__ out, int splitk)
{
    int idx = blockIdx.x * 256 + threadIdx.x;   // < 524288
    float s = bias[idx & 255];
    for (int sk = 0; sk < splitk; ++sk) s += partial[(size_t)sk * (NTOK * COUT) + idx];
    out[idx] = s;
}

extern "C" void kernel_launch(void* const* d_in, const int* in_sizes, int n_in,
                              void* d_out, int out_size, void* d_ws, size_t ws_size,
                              hipStream_t stream)
{
    const float* x     = (const float*)d_in[0];
    const float* map_w = (const float*)d_in[1];
    const float* map_b = (const float*)d_in[2];
    const float* cent  = (const float*)d_in[3];
    const float* pw_w  = (const float*)d_in[4];
    const float* pw_B  = (const float*)d_in[5];
    float* out = (float*)d_out;

    char* ws = (char*)d_ws;
    float* resp           = (float*)ws;                       // 512 KB
    float* commit         = (float*)(ws + 524288);            // 8 KB
    unsigned short* Bp    = (unsigned short*)(ws + (1u << 20));   // 8 MB bf16 packed B
    float* partial        = (float*)(ws + (10u << 20));       // splitk * 2 MB

    int splitk = 16;
    while (splitk > 1 &&
           (size_t)(10u << 20) + (size_t)splitk * (size_t)(NTOK * COUT * 4) > ws_size)
        splitk >>= 1;

    pack_b_kernel<<<4096, 256, 0, stream>>>(pw_w, Bp);
    vq_kernel<<<2048, 64, 0, stream>>>(x, map_w, map_b, cent, resp, commit);
    loss_kernel<<<1, 1024, 0, stream>>>(resp, commit, out + NTOK * COUT);
    gemm_kernel<<<dim3(32, splitk), 256, 0, stream>>>(x, resp, Bp, partial, 256 / splitk);
    reduce_kernel<<<2048, 256, 0, stream>>>(partial, pw_B, out, splitk);
}

// Round 2
// 86.910 us; speedup vs baseline: 1.0946x; 1.0946x over previous
//
#include <hip/hip_runtime.h>
#include <stdint.h>

#define CIN   256
#define COUT  256
#define NE    64
#define RD    64
#define NTOK  2048

typedef __attribute__((ext_vector_type(8))) short bf16x8;
typedef __attribute__((ext_vector_type(4))) float f32x4;

// ---------- helpers ----------
__device__ inline unsigned short f2bf(float f) {
    uint32_t u = __float_as_uint(f);
    uint32_t r = (u + 0x7FFFu + ((u >> 16) & 1u)) >> 16;   // RNE, finite inputs
    return (unsigned short)r;
}

__device__ inline float wave_sum(float v) {
    #pragma unroll
    for (int m = 1; m < 64; m <<= 1) v += __shfl_xor(v, m, 64);
    return v;
}
__device__ inline float wave_max(float v) {
    #pragma unroll
    for (int m = 1; m < 64; m <<= 1) v = fmaxf(v, __shfl_xor(v, m, 64));
    return v;
}

__device__ inline uint32_t rotl32(uint32_t v, int d) { return (v << d) | (v >> (32 - d)); }

// Threefry-2x32, key = (0, 42), matching JAX's threefry2x32 exactly.
__device__ inline void threefry_0_42(uint32_t c0, uint32_t c1, uint32_t& o0, uint32_t& o1) {
    const uint32_t ks0 = 0u, ks1 = 42u, ks2 = 0u ^ 42u ^ 0x1BD11BDAu;
    uint32_t x0 = c0 + ks0, x1 = c1 + ks1;
#define TF_R(r) { x0 += x1; x1 = rotl32(x1, r); x1 ^= x0; }
    TF_R(13) TF_R(15) TF_R(26) TF_R(6)
    x0 += ks1; x1 += ks2 + 1u;
    TF_R(17) TF_R(29) TF_R(16) TF_R(24)
    x0 += ks2; x1 += ks0 + 2u;
    TF_R(13) TF_R(15) TF_R(26) TF_R(6)
    x0 += ks0; x1 += ks1 + 3u;
    TF_R(17) TF_R(29) TF_R(16) TF_R(24)
    x0 += ks1; x1 += ks2 + 4u;
    TF_R(13) TF_R(15) TF_R(26) TF_R(6)
    x0 += ks2; x1 += ks0 + 5u;
#undef TF_R
    o0 = x0; o1 = x1;
}

// ---------- kernel 1: pack pw_w fp32 -> Bp bf16, GEMM-ready swizzled tile image ----------
// Bp is 512 tiles of 16 KB, tile t = e*8 + kc (expert e, K-chunk kc of 32).
// Tile image byte b: row(n)=b>>6, granule g'=(b>>4)&3, holds k16 = g' ^ ((row>>1)&3),
// i.e. elements pw_w[e, row*256 + kc*32 + k16*8 .. +7].  (swizzle pre-baked so
// global_load_lds can write LDS linearly while ds_read_b128 reads conflict-free)
__global__ __launch_bounds__(256) void pack_b_kernel(const float* __restrict__ pw,
                                                     unsigned short* __restrict__ Bp) {
    int G = blockIdx.x * 256 + threadIdx.x;   // 16B-granule id, 524288 total
    int tile = G >> 10, qg = G & 1023;
    int e = tile >> 3, kc = tile & 7;
    int row = qg >> 2, gp = qg & 3;
    int k16 = gp ^ ((row >> 1) & 3);
    const float* s = pw + ((size_t)e << 16) + (row << 8) + (kc << 5) + (k16 << 3);
    float4 v0 = *(const float4*)s;
    float4 v1 = *(const float4*)(s + 4);
    ushort4 a, b;
    a.x = f2bf(v0.x); a.y = f2bf(v0.y); a.z = f2bf(v0.z); a.w = f2bf(v0.w);
    b.x = f2bf(v1.x); b.y = f2bf(v1.y); b.z = f2bf(v1.z); b.w = f2bf(v1.w);
    *(ushort4*)(Bp + ((size_t)G << 3)) = a;
    *(ushort4*)(Bp + ((size_t)G << 3) + 4) = b;
}

// ---------- kernel 2: per-token VQ (unchanged, verified round 1) ----------
__global__ __launch_bounds__(64) void vq_kernel(
    const float* __restrict__ x, const float* __restrict__ mw,
    const float* __restrict__ mb, const float* __restrict__ cent,
    float* __restrict__ resp_out, float* __restrict__ commit_out)
{
    __shared__ float xs[CIN];
    __shared__ float cs[NE][RD + 1];
    __shared__ float ksh[RD];
    __shared__ float rs[NE];

    const int tb = blockIdx.x;
    const int t  = threadIdx.x;

    ((float4*)xs)[t] = ((const float4*)(x + (size_t)tb * CIN))[t];
    #pragma unroll
    for (int j = 0; j < 16; ++j) {
        int fidx = (j << 6) + t;
        float4 v = ((const float4*)cent)[fidx];
        int row = fidx >> 4, c0 = (fidx & 15) << 2;
        cs[row][c0] = v.x; cs[row][c0 + 1] = v.y; cs[row][c0 + 2] = v.z; cs[row][c0 + 3] = v.w;
    }
    __syncthreads();

    float kr = mb[t];
    const float4* mwr = (const float4*)(mw + (size_t)t * CIN);
    #pragma unroll 8
    for (int j = 0; j < 64; ++j) {
        float4 wv = mwr[j];
        kr += wv.x * xs[(j << 2)] + wv.y * xs[(j << 2) + 1]
            + wv.z * xs[(j << 2) + 2] + wv.w * xs[(j << 2) + 3];
    }
    ksh[t] = kr;
    float kk = wave_sum(kr * kr);
    __syncthreads();

    float cc = 0.f, dt = 0.f;
    #pragma unroll 8
    for (int r = 0; r < 64; ++r) {
        float cv = cs[t][r];
        cc += cv * cv;
        dt += ksh[r] * cv;
    }
    float d = kk + cc - 2.f * dt;

    uint32_t fidx = (uint32_t)((tb << 6) + t);
    uint32_t cnt  = fidx < 65536u ? fidx : fidx - 65536u;
    uint32_t o0, o1;
    threefry_0_42(cnt, cnt + 65536u, o0, o1);
    uint32_t bits = fidx < 65536u ? o0 : o1;
    float uf = __uint_as_float((bits >> 9) | 0x3f800000u) - 1.0f;
    uf = fmaxf(uf, 1.17549435e-38f);
    float g = -logf(-logf(uf));

    float sv = (g - d) * 1.0f;
    float mx = wave_max(sv);
    float p  = expf(sv - mx);
    float ps = wave_sum(p);
    float rv = p / ps;
    resp_out[(tb << 6) + t] = rv;
    rs[t] = rv;
    __syncthreads();

    float q = 0.f;
    #pragma unroll 8
    for (int e2 = 0; e2 < 64; ++e2) q += rs[e2] * cs[e2][t];
    float df = kr - q;
    float sq = wave_sum(df * df);
    if (t == 0) commit_out[tb] = sq;
}

// ---------- kernel 3: loss scalar (unchanged, verified round 1) ----------
__global__ __launch_bounds__(1024) void loss_kernel(const float* __restrict__ resp,
                                                    const float* __restrict__ commit_part,
                                                    float* __restrict__ loss_out)
{
    const int t = threadIdx.x;
    const int e = t & 63, wv = t >> 6;
    float s0 = 0, s1 = 0, s2 = 0, s3 = 0;
    for (int r = wv; r < NTOK; r += 64) {
        s0 += resp[(r)      * 64 + e];
        s1 += resp[(r + 16) * 64 + e];
        s2 += resp[(r + 32) * 64 + e];
        s3 += resp[(r + 48) * 64 + e];
    }
    __shared__ float pss[16][64];
    __shared__ float cps[1024];
    pss[wv][e] = (s0 + s1) + (s2 + s3);
    float csum = 0;
    for (int i = t; i < NTOK; i += 1024) csum += commit_part[i];
    cps[t] = csum;
    __syncthreads();
    if (t < 64) {
        float imp = 0, ct = 0;
        #pragma unroll
        for (int g2 = 0; g2 < 16; ++g2) { imp += pss[g2][t]; ct += cps[(g2 << 6) + t]; }
        ct = wave_sum(ct);
        float tot  = wave_sum(imp);
        float mean = tot * (1.0f / 64.f);
        float dv   = imp - mean;
        float var  = wave_sum(dv * dv) * (1.0f / 63.f);
        if (t == 0) {
            float mse = ct * (1.0f / (float)(NTOK * RD));
            float imp_loss = sqrtf(var) / mean;
            loss_out[0] = (0.25f + 1.0f) * mse + 30.0f * imp_loss;
        }
    }
}

// ---------- kernel 4: MoE GEMM, per-expert epilogue weighting ----------
// Block = (m-tile of 64 rows) x (e-group of 8 experts). K per expert = 256.
// A = bf16(x[m-tile, :]) staged in LDS ONCE (unscaled). Per expert: inner GEMM
// into P-acc; epilogue O += resp[m,e]*P. Partials per e-group; reduce adds 8.
__device__ inline void stage_b_tile(char* dst, const char* src, int w, int lane) {
    #pragma unroll
    for (int i = 0; i < 4; ++i) {
        const int off = (w << 12) + (i << 10);
        __builtin_amdgcn_global_load_lds(
            (const __attribute__((address_space(1))) unsigned int*)(src + off + (lane << 4)),
            (__attribute__((address_space(3))) unsigned int*)(dst + off), 16, 0, 0);
    }
}

__global__ __launch_bounds__(256, 1) void gemm_kernel(
    const float* __restrict__ x, const float* __restrict__ resp,
    const unsigned short* __restrict__ Bp, float* __restrict__ partial)
{
    __shared__ char lds[65536];
    char* As  = lds;             // 32 KB: [64 rows][32 granules of 16B], slot^=(row&7)
    char* Bs0 = lds + 32768;     // 16 KB: [256 rows][4 granules], g'=q^((row>>1)&3)
    char* Bs1 = lds + 49152;

    const int tid  = threadIdx.x;
    const int lane = tid & 63;
    const int w    = tid >> 6;
    const int lo   = lane & 15, kq = lane >> 4;
    const int g    = blockIdx.x & 7;            // e-group -> XCD-local B slice
    const int m0   = (blockIdx.x >> 3) << 6;

    // ---- stage A: x[m0..m0+63, 0:256] fp32 -> bf16, swizzled ----
    {
        const float4* x4 = (const float4*)(x + (size_t)m0 * CIN);
        #pragma unroll
        for (int it = 0; it < 16; ++it) {
            int i = (it << 8) + tid;            // float4 index, coalesced
            float4 v = x4[i];
            int row = i >> 6, k4 = i & 63;
            int slot = k4 >> 1, half = k4 & 1;
            ushort4 u;
            u.x = f2bf(v.x); u.y = f2bf(v.y); u.z = f2bf(v.z); u.w = f2bf(v.w);
            *(ushort4*)(As + (row << 9) + ((slot ^ (row & 7)) << 4) + (half << 3)) = u;
        }
    }

    const char* bsrc = (const char*)Bp + ((size_t)g << 20);   // this group's 1 MB slice
    stage_b_tile(Bs0, bsrc, w, lane);
    __syncthreads();   // A writes + B tile 0 drained

    f32x4 P[4][4] = {};
    f32x4 O[4][4] = {};
    const f32x4 z = {};

    auto compute = [&](char* cur, int t) {
        const int kc = t & 7;
        bf16x8 af[4], bfr[4];
        #pragma unroll
        for (int mi = 0; mi < 4; ++mi) {
            int row = (mi << 4) + lo;
            af[mi] = *(const bf16x8*)(As + (row << 9) + ((((kc << 2) + kq) ^ (row & 7)) << 4));
        }
        #pragma unroll
        for (int ni = 0; ni < 4; ++ni) {
            int row = (w << 6) + (ni << 4) + lo;
            bfr[ni] = *(const bf16x8*)(cur + (row << 6) + ((kq ^ ((row >> 1) & 3)) << 4));
        }
        #pragma unroll
        for (int mi = 0; mi < 4; ++mi)
            #pragma unroll
            for (int ni = 0; ni < 4; ++ni)
                P[mi][ni] = __builtin_amdgcn_mfma_f32_16x16x32_bf16(
                    af[mi], bfr[ni], P[mi][ni], 0, 0, 0);
        if (kc == 7) {   // expert done: O += resp * P; P = 0
            const int e = (g << 3) + (t >> 3);
            float r[4][4];
            const float* rb = resp + ((size_t)(m0 + (kq << 2)) << 6) + e;
            #pragma unroll
            for (int mi = 0; mi < 4; ++mi)
                #pragma unroll
                for (int j = 0; j < 4; ++j)
                    r[mi][j] = rb[(size_t)(((mi << 4) + j)) << 6];
            #pragma unroll
            for (int mi = 0; mi < 4; ++mi)
                #pragma unroll
                for (int ni = 0; ni < 4; ++ni) {
                    #pragma unroll
                    for (int j = 0; j < 4; ++j)
                        O[mi][ni][j] += r[mi][j] * P[mi][ni][j];
                    P[mi][ni] = z;
                }
        }
    };

    for (int t = 0; t < 64; t += 2) {
        stage_b_tile(Bs1, bsrc + ((size_t)(t + 1) << 14), w, lane);
        compute(Bs0, t);
        __syncthreads();
        if (t + 2 < 64)
            stage_b_tile(Bs0, bsrc + ((size_t)(t + 2) << 14), w, lane);
        compute(Bs1, t + 1);
        __syncthreads();
    }

    // ---- write partial [g][2048][256] ----
    float* pout = partial + ((size_t)g << 19)
                + ((size_t)(m0 + (kq << 2)) << 8) + (w << 6) + lo;
    #pragma unroll
    for (int mi = 0; mi < 4; ++mi)
        #pragma unroll
        for (int j = 0; j < 4; ++j) {
            float* pr = pout + ((size_t)((mi << 4) + j) << 8);
            #pragma unroll
            for (int ni = 0; ni < 4; ++ni)
                pr[ni << 4] = O[mi][ni][j];
        }
}

// ---------- kernel 5: reduce 8 e-group partials + bias ----------
__global__ __launch_bounds__(256) void reduce_kernel(const float* __restrict__ partial,
                                                     const float* __restrict__ bias,
                                                     float* __restrict__ out)
{
    int idx = blockIdx.x * 256 + threadIdx.x;   // < 524288
    float s = bias[idx & 255];
    #pragma unroll
    for (int g = 0; g < 8; ++g) s += partial[((size_t)g << 19) + idx];
    out[idx] = s;
}

extern "C" void kernel_launch(void* const* d_in, const int* in_sizes, int n_in,
                              void* d_out, int out_size, void* d_ws, size_t ws_size,
                              hipStream_t stream)
{
    const float* x     = (const float*)d_in[0];
    const float* map_w = (const float*)d_in[1];
    const float* map_b = (const float*)d_in[2];
    const float* cent  = (const float*)d_in[3];
    const float* pw_w  = (const float*)d_in[4];
    const float* pw_B  = (const float*)d_in[5];
    float* out = (float*)d_out;

    char* ws = (char*)d_ws;
    float* resp        = (float*)ws;                      // 512 KB
    float* commit      = (float*)(ws + 524288);           // 8 KB
    unsigned short* Bp = (unsigned short*)(ws + (1u << 20));  // 8 MB packed B
    float* partial     = (float*)(ws + (10u << 20));      // 8 * 2 MB = 16 MB

    pack_b_kernel<<<2048, 256, 0, stream>>>(pw_w, Bp);
    vq_kernel<<<2048, 64, 0, stream>>>(x, map_w, map_b, cent, resp, commit);
    gemm_kernel<<<256, 256, 0, stream>>>(x, resp, Bp, partial);
    reduce_kernel<<<2048, 256, 0, stream>>>(partial, pw_B, out);
    loss_kernel<<<1, 1024, 0, stream>>>(resp, commit, out + NTOK * COUT);
}

// Round 3
// 68.291 us; speedup vs baseline: 1.3931x; 1.2726x over previous
//
#include <hip/hip_runtime.h>
#include <stdint.h>

#define CIN   256
#define COUT  256
#define NE    64
#define RD    64
#define NTOK  2048

typedef __attribute__((ext_vector_type(8))) short bf16x8;
typedef __attribute__((ext_vector_type(4))) float f32x4;

// ---------- helpers ----------
__device__ inline unsigned short f2bf(float f) {
    uint32_t u = __float_as_uint(f);
    uint32_t r = (u + 0x7FFFu + ((u >> 16) & 1u)) >> 16;   // RNE, finite inputs
    return (unsigned short)r;
}

__device__ inline float wave_sum(float v) {
    #pragma unroll
    for (int m = 1; m < 64; m <<= 1) v += __shfl_xor(v, m, 64);
    return v;
}
__device__ inline float wave_max(float v) {
    #pragma unroll
    for (int m = 1; m < 64; m <<= 1) v = fmaxf(v, __shfl_xor(v, m, 64));
    return v;
}

__device__ inline uint32_t rotl32(uint32_t v, int d) { return (v << d) | (v >> (32 - d)); }

// Threefry-2x32, key = (0, 42), matching JAX's threefry2x32 exactly.
__device__ inline void threefry_0_42(uint32_t c0, uint32_t c1, uint32_t& o0, uint32_t& o1) {
    const uint32_t ks0 = 0u, ks1 = 42u, ks2 = 0u ^ 42u ^ 0x1BD11BDAu;
    uint32_t x0 = c0 + ks0, x1 = c1 + ks1;
#define TF_R(r) { x0 += x1; x1 = rotl32(x1, r); x1 ^= x0; }
    TF_R(13) TF_R(15) TF_R(26) TF_R(6)
    x0 += ks1; x1 += ks2 + 1u;
    TF_R(17) TF_R(29) TF_R(16) TF_R(24)
    x0 += ks2; x1 += ks0 + 2u;
    TF_R(13) TF_R(15) TF_R(26) TF_R(6)
    x0 += ks0; x1 += ks1 + 3u;
    TF_R(17) TF_R(29) TF_R(16) TF_R(24)
    x0 += ks1; x1 += ks2 + 4u;
    TF_R(13) TF_R(15) TF_R(26) TF_R(6)
    x0 += ks2; x1 += ks0 + 5u;
#undef TF_R
    o0 = x0; o1 = x1;
}

// ---------- kernel 1: pack pw_w fp32 -> Bp bf16, GEMM-ready swizzled tile image ----------
// Bp = 512 tiles of 16 KB, tile t = e*8 + kc. Tile byte b: row(n)=b>>6, granule
// g'=(b>>4)&3 holds k16 = g' ^ ((row>>1)&3)  (swizzle pre-baked: linear
// global_load_lds dest + conflict-free ds_read_b128).
__global__ __launch_bounds__(256) void pack_b_kernel(const float* __restrict__ pw,
                                                     unsigned short* __restrict__ Bp) {
    int G = blockIdx.x * 256 + threadIdx.x;   // 16B-granule id, 524288 total
    int tile = G >> 10, qg = G & 1023;
    int e = tile >> 3, kc = tile & 7;
    int row = qg >> 2, gp = qg & 3;
    int k16 = gp ^ ((row >> 1) & 3);
    const float* s = pw + ((size_t)e << 16) + (row << 8) + (kc << 5) + (k16 << 3);
    float4 v0 = *(const float4*)s;
    float4 v1 = *(const float4*)(s + 4);
    ushort4 a, b;
    a.x = f2bf(v0.x); a.y = f2bf(v0.y); a.z = f2bf(v0.z); a.w = f2bf(v0.w);
    b.x = f2bf(v1.x); b.y = f2bf(v1.y); b.z = f2bf(v1.z); b.w = f2bf(v1.w);
    *(ushort4*)(Bp + ((size_t)G << 3)) = a;
    *(ushort4*)(Bp + ((size_t)G << 3) + 4) = b;
}

// ---------- kernel 2: VQ, 4 tokens per block (one per wave) ----------
__global__ __launch_bounds__(256) void vq_kernel(
    const float* __restrict__ x, const float* __restrict__ mw,
    const float* __restrict__ mb, const float* __restrict__ cent,
    float* __restrict__ resp_out, float* __restrict__ commit_out)
{
    __shared__ float xs[4][CIN];
    __shared__ float cs[NE][RD + 1];
    __shared__ float ksh[4][RD];
    __shared__ float rs[4][NE];

    const int tid = threadIdx.x;
    const int w   = tid >> 6;          // wave = token slot
    const int t   = tid & 63;          // lane
    const int tb  = (blockIdx.x << 2) + w;

    ((float4*)xs[w])[t] = ((const float4*)(x + (size_t)tb * CIN))[t];
    #pragma unroll
    for (int j = 0; j < 4; ++j) {
        int fidx = (j << 8) + tid;                 // 1024 float4s of centroids
        float4 v = ((const float4*)cent)[fidx];
        int row = fidx >> 4, c0 = (fidx & 15) << 2;
        cs[row][c0] = v.x; cs[row][c0 + 1] = v.y; cs[row][c0 + 2] = v.z; cs[row][c0 + 3] = v.w;
    }
    __syncthreads();

    // k[t] = x_row . map_w[t] + map_b[t]
    float kr = mb[t];
    const float4* mwr = (const float4*)(mw + (size_t)t * CIN);
    #pragma unroll 8
    for (int j = 0; j < 64; ++j) {
        float4 wv = mwr[j];
        kr += wv.x * xs[w][(j << 2)] + wv.y * xs[w][(j << 2) + 1]
            + wv.z * xs[w][(j << 2) + 2] + wv.w * xs[w][(j << 2) + 3];
    }
    ksh[w][t] = kr;
    float kk = wave_sum(kr * kr);
    __syncthreads();

    float cc = 0.f, dt = 0.f;
    #pragma unroll 8
    for (int r = 0; r < 64; ++r) {
        float cv = cs[t][r];
        cc += cv * cv;
        dt += ksh[w][r] * cv;
    }
    float d = kk + cc - 2.f * dt;

    // gumbel noise, bit-exact with jax.random.gumbel(key(42), (2048,64), f32)
    uint32_t fidx = (uint32_t)((tb << 6) + t);
    uint32_t cnt  = fidx < 65536u ? fidx : fidx - 65536u;
    uint32_t o0, o1;
    threefry_0_42(cnt, cnt + 65536u, o0, o1);
    uint32_t bits = fidx < 65536u ? o0 : o1;
    float uf = __uint_as_float((bits >> 9) | 0x3f800000u) - 1.0f;
    uf = fmaxf(uf, 1.17549435e-38f);
    float g = -logf(-logf(uf));

    float sv = g - d;                  // TAU = 1
    float mx = wave_max(sv);
    float p  = expf(sv - mx);
    float ps = wave_sum(p);
    float rv = p / ps;
    resp_out[(tb << 6) + t] = rv;
    rs[w][t] = rv;
    __syncthreads();

    float q = 0.f;
    #pragma unroll 8
    for (int e2 = 0; e2 < 64; ++e2) q += rs[w][e2] * cs[e2][t];
    float df = kr - q;
    float sq = wave_sum(df * df);
    if (t == 0) commit_out[tb] = sq;
}

// ---------- kernel 3a: loss partials (32 blocks x 64 tokens) ----------
__global__ __launch_bounds__(256) void loss_part_kernel(const float* __restrict__ resp,
                                                        const float* __restrict__ commit_part,
                                                        float* __restrict__ imp_p,
                                                        float* __restrict__ cm_p)
{
    const int b = blockIdx.x, t = threadIdx.x;
    const int e = t & 63, grp = t >> 6;
    float s = 0.f;
    #pragma unroll
    for (int j = 0; j < 16; ++j)
        s += resp[(size_t)((b << 6) + (grp << 4) + j) * 64 + e];
    __shared__ float part[4][64];
    part[grp][e] = s;
    __syncthreads();
    if (t < 64) {
        float v = part[0][t] + part[1][t] + part[2][t] + part[3][t];
        imp_p[(b << 6) + t] = v;
        float cm = commit_part[(b << 6) + t];
        cm = wave_sum(cm);
        if (t == 0) cm_p[b] = cm;
    }
}

// ---------- kernel 3b: final loss scalar ----------
__global__ __launch_bounds__(64) void loss_final_kernel(const float* __restrict__ imp_p,
                                                        const float* __restrict__ cm_p,
                                                        float* __restrict__ loss_out)
{
    const int t = threadIdx.x;
    float imp = 0.f;
    #pragma unroll
    for (int b = 0; b < 32; ++b) imp += imp_p[(b << 6) + t];
    float ct = (t < 32) ? cm_p[t] : 0.f;
    ct = wave_sum(ct);
    float tot  = wave_sum(imp);
    float mean = tot * (1.0f / 64.f);
    float dv   = imp - mean;
    float var  = wave_sum(dv * dv) * (1.0f / 63.f);
    if (t == 0) {
        float mse = ct * (1.0f / (float)(NTOK * RD));
        float imp_loss = sqrtf(var) / mean;
        // commitment and kmeans losses are numerically identical forward
        loss_out[0] = (0.25f + 1.0f) * mse + 30.0f * imp_loss;
    }
}

// ---------- kernel 4: MoE GEMM, per-expert epilogue weighting ----------
// Block = (m-tile of 32 rows) x (e-group of 8 experts), grid 64x8 = 512 (2/CU).
// A = bf16(x) staged once (16 KB). Phase = BK 64 (two 16 KB B tiles, dbuf).
// Per expert (4 phases): P-acc; epilogue O += resp[m,e]*P.
__device__ inline void stage_b32(char* dst, const char* src, int w, int lane) {
    #pragma unroll
    for (int i = 0; i < 8; ++i) {
        const int off = (w << 13) + (i << 10);
        __builtin_amdgcn_global_load_lds(
            (const __attribute__((address_space(1))) unsigned int*)(src + off + (lane << 4)),
            (__attribute__((address_space(3))) unsigned int*)(dst + off), 16, 0, 0);
    }
}

__global__ __launch_bounds__(256) void gemm_kernel(
    const float* __restrict__ x, const float* __restrict__ resp,
    const unsigned short* __restrict__ Bp, float* __restrict__ partial)
{
    __shared__ char lds[81920];
    char* As  = lds;             // 16 KB: [32 rows][32 slots of 16B], slot^=(row&7)
    char* Bs0 = lds + 16384;     // 32 KB: two 16KB tiles [256 rows][4 gran], g'=kq^((row>>1)&3)
    char* Bs1 = lds + 49152;

    const int tid  = threadIdx.x;
    const int lane = tid & 63;
    const int w    = tid >> 6;
    const int lo   = lane & 15, kq = lane >> 4;
    const int g    = blockIdx.x & 7;            // e-group -> XCD-local B slice
    const int m0   = (blockIdx.x >> 3) << 5;

    // ---- stage A: x[m0..m0+31, 0:256] fp32 -> bf16, swizzled ----
    {
        const float4* x4 = (const float4*)(x + (size_t)m0 * CIN);
        #pragma unroll
        for (int it = 0; it < 8; ++it) {
            int i = (it << 8) + tid;            // float4 index, coalesced
            float4 v = x4[i];
            int row = i >> 6, k4 = i & 63;
            int slot = k4 >> 1, half = k4 & 1;
            ushort4 u;
            u.x = f2bf(v.x); u.y = f2bf(v.y); u.z = f2bf(v.z); u.w = f2bf(v.w);
            *(ushort4*)(As + (row << 9) + ((slot ^ (row & 7)) << 4) + (half << 3)) = u;
        }
    }

    const char* bsrc = (const char*)Bp + ((size_t)g << 20);   // this group's 1 MB slice
    stage_b32(Bs0, bsrc, w, lane);
    __syncthreads();   // A writes + B phase 0 drained

    f32x4 P[2][4] = {};
    f32x4 O[2][4] = {};
    const f32x4 z = {};

    char* cur = Bs0;
    char* nxt = Bs1;

    for (int p = 0; p < 32; ++p) {
        if (p + 1 < 32) stage_b32(nxt, bsrc + ((size_t)(p + 1) << 15), w, lane);

        #pragma unroll
        for (int sub = 0; sub < 2; ++sub) {
            const int kc = ((p & 3) << 1) + sub;       // k-chunk within expert, 0..7
            char* bt = cur + (sub << 14);
            bf16x8 af[2], bfr[4];
            #pragma unroll
            for (int mi = 0; mi < 2; ++mi) {
                int row = (mi << 4) + lo;
                af[mi] = *(const bf16x8*)(As + (row << 9) + ((((kc << 2) + kq) ^ (row & 7)) << 4));
            }
            #pragma unroll
            for (int ni = 0; ni < 4; ++ni) {
                int row = (w << 6) + (ni << 4) + lo;
                bfr[ni] = *(const bf16x8*)(bt + (row << 6) + ((kq ^ ((row >> 1) & 3)) << 4));
            }
            #pragma unroll
            for (int mi = 0; mi < 2; ++mi)
                #pragma unroll
                for (int ni = 0; ni < 4; ++ni)
                    P[mi][ni] = __builtin_amdgcn_mfma_f32_16x16x32_bf16(
                        af[mi], bfr[ni], P[mi][ni], 0, 0, 0);
        }

        if ((p & 3) == 3) {   // expert done: O += resp * P; P = 0
            const int e = (g << 3) + (p >> 2);
            float r[2][4];
            const float* rb = resp + ((size_t)(m0 + (kq << 2)) << 6) + e;
            #pragma unroll
            for (int mi = 0; mi < 2; ++mi)
                #pragma unroll
                for (int j = 0; j < 4; ++j)
                    r[mi][j] = rb[(size_t)((mi << 4) + j) << 6];
            #pragma unroll
            for (int mi = 0; mi < 2; ++mi)
                #pragma unroll
                for (int ni = 0; ni < 4; ++ni) {
                    #pragma unroll
                    for (int j = 0; j < 4; ++j)
                        O[mi][ni][j] += r[mi][j] * P[mi][ni][j];
                    P[mi][ni] = z;
                }
        }
        __syncthreads();
        char* tmp = cur; cur = nxt; nxt = tmp;
    }

    // ---- write partial [g][2048][256] ----
    float* pout = partial + ((size_t)g << 19)
                + ((size_t)(m0 + (kq << 2)) << 8) + (w << 6) + lo;
    #pragma unroll
    for (int mi = 0; mi < 2; ++mi)
        #pragma unroll
        for (int j = 0; j < 4; ++j) {
            float* pr = pout + ((size_t)((mi << 4) + j) << 8);
            #pragma unroll
            for (int ni = 0; ni < 4; ++ni)
                pr[ni << 4] = O[mi][ni][j];
        }
}

// ---------- kernel 5: reduce 8 e-group partials + bias (float4) ----------
__global__ __launch_bounds__(256) void reduce_kernel(const float* __restrict__ partial,
                                                     const float* __restrict__ bias,
                                                     float* __restrict__ out)
{
    int idx = blockIdx.x * 256 + threadIdx.x;   // float4 id, < 131072
    float4 s = ((const float4*)bias)[idx & 63];
    #pragma unroll
    for (int g = 0; g < 8; ++g) {
        float4 v = ((const float4*)partial)[((size_t)g << 17) + idx];
        s.x += v.x; s.y += v.y; s.z += v.z; s.w += v.w;
    }
    ((float4*)out)[idx] = s;
}

extern "C" void kernel_launch(void* const* d_in, const int* in_sizes, int n_in,
                              void* d_out, int out_size, void* d_ws, size_t ws_size,
                              hipStream_t stream)
{
    const float* x     = (const float*)d_in[0];
    const float* map_w = (const float*)d_in[1];
    const float* map_b = (const float*)d_in[2];
    const float* cent  = (const float*)d_in[3];
    const float* pw_w  = (const float*)d_in[4];
    const float* pw_B  = (const float*)d_in[5];
    float* out = (float*)d_out;

    char* ws = (char*)d_ws;
    float* resp        = (float*)ws;                          // 512 KB
    float* commit      = (float*)(ws + 524288);               // 8 KB
    float* imp_p       = (float*)(ws + 540672);               // 8 KB
    float* cm_p        = (float*)(ws + 557056);               // 128 B
    unsigned short* Bp = (unsigned short*)(ws + (1u << 20));  // 8 MB packed B
    float* partial     = (float*)(ws + (10u << 20));          // 8 * 2 MB = 16 MB

    pack_b_kernel<<<2048, 256, 0, stream>>>(pw_w, Bp);
    vq_kernel<<<512, 256, 0, stream>>>(x, map_w, map_b, cent, resp, commit);
    gemm_kernel<<<512, 256, 0, stream>>>(x, resp, Bp, partial);
    reduce_kernel<<<512, 256, 0, stream>>>(partial, pw_B, out);
    loss_part_kernel<<<32, 256, 0, stream>>>(resp, commit, imp_p, cm_p);
    loss_final_kernel<<<1, 64, 0, stream>>>(imp_p, cm_p, out + NTOK * COUT);
}